// Round 2
// baseline (375.274 us; speedup 1.0000x reference)
//
#include <hip/hip_runtime.h>

// Problem constants
#define DD 20          // hypervol spatial extent per axis
#define MM 32          // channel count m
#define OO 19          // output extent per axis (DD - RANK + 1, RANK=2)
#define NBLK (OO*OO*OO)

// workspace layout (floats):
//   Ct[19][32][32]  transposed cosine table: Ct[k][j][i] = cos(2*pi*k/(i*32+j+2))
//   Pt[32][32]      P transposed:  Pt[j][i] = P[i][j]
//   Mt[32][32]      M_w transposed: Mt[j][i] = M_w[i][j]
#define CT_FLOATS (OO*MM*MM)         // 19456
#define PT_OFF CT_FLOATS             // 19456
#define MT_OFF (PT_OFF + MM*MM)      // 20480
#define WS_FLOATS (MT_OFF + MM*MM)   // 21504

#define SWS 36   // padded LDS row stride (floats): 144B, 16B-aligned, not bank-aligned

__global__ __launch_bounds__(256) void build_tables_kernel(
        const float* __restrict__ Mw, const float* __restrict__ P,
        float* __restrict__ ws) {
    int idx = blockIdx.x * 256 + threadIdx.x;
    if (idx < CT_FLOATS) {
        int k = idx >> 10;        // axis position 0..18
        int r = idx & 1023;
        int j = r >> 5;           // transposed: slow index is j
        int i = r & 31;
        float period = (float)(i * MM + j + 2);
        ws[idx] = cosf(6.28318530717958647692f * (float)k / period);
    } else if (idx < MT_OFF) {
        int r = idx - PT_OFF;
        ws[idx] = P[(r & 31) * MM + (r >> 5)];     // Pt[j][i] = P[i][j]
    } else if (idx < WS_FLOATS) {
        int r = idx - MT_OFF;
        ws[idx] = Mw[(r & 31) * MM + (r >> 5)];    // Mt[j][i] = Mw[i][j]
    }
}

// One block per (a,b,c). 256 threads: i2 = tid&15 (i = 2*i2 channel pair),
// g = tid>>4 (16 d-groups). d-ownership: g<3 own {2g,2g+1}, g>=3 own {g+3}
// (doubles concentrated in wave 0 -> minimal total wave-iterations).
__global__ __launch_bounds__(256) void spatial_kernel(
        const float* __restrict__ H, const float* __restrict__ ws,
        float* __restrict__ out) {
    __shared__ float sS[DD * MM];      // (a,b,c)-window pre-sums per d    (2560 B)
    __shared__ float sW[OO * SWS];     // win rows /16, padded             (2736 B)
    __shared__ float sX[OO * SWS];     // x rows, padded                   (2736 B)
    __shared__ float sMt[MM * MM];     // Mt staged                        (4096 B)

    const int tid = threadIdx.x;
    const int i2  = tid & 15;
    const int i   = i2 * 2;
    const int g   = tid >> 4;
    const int d0  = (g < 3) ? (2 * g) : (g + 3);
    const int d1  = d0 + ((g < 3) ? 2 : 1);

    // XCD-contiguous swizzle: dispatch round-robins blocks over 8 XCDs;
    // remap so each XCD's share is a contiguous (a,b,c) slab (~3.4MB of H < 4MB L2).
    // 6859 = 3*858 + 5*857 (bijective split).
    const int raw = blockIdx.x;
    const int xcd = raw & 7;
    const int k   = raw >> 3;
    const int blk = (xcd < 3) ? (xcd * 858 + k) : (2574 + (xcd - 3) * 857 + k);
    const int c = blk % OO;
    const int b = (blk / OO) % OO;
    const int a = blk / (OO * OO);

    const float* __restrict__ Ct = ws;
    const float* __restrict__ Pt = ws + PT_OFF;
    const float* __restrict__ Mt = ws + MT_OFF;

    // stage Mt (coalesced, 1 float4/thread)
    ((float4*)sMt)[tid] = ((const float4*)Mt)[tid];

    // qp[j] = Pt[j][i:i+2] * Ct[a][j][i:i+2] * Ct[b][..] * Ct[c][..]  (registers)
    float2 qp[MM];
    {
        const float2* p  = (const float2*)(Pt + i);
        const float2* ca = (const float2*)(Ct + a * (MM * MM) + i);
        const float2* cb = (const float2*)(Ct + b * (MM * MM) + i);
        const float2* cc = (const float2*)(Ct + c * (MM * MM) + i);
        #pragma unroll
        for (int j = 0; j < MM; ++j) {
            float2 pv = p[j * 16];
            float2 va = ca[j * 16];
            float2 vb = cb[j * 16];
            float2 vc = cc[j * 16];
            qp[j].x = pv.x * va.x * vb.x * vc.x;
            qp[j].y = pv.y * va.y * vb.y * vc.y;
        }
    }

    // phase 1: 8-shift pre-sum over (a,b,c), float4 loads. thread = (dd, quad)
    {
        const int dd = tid >> 3;   // 0..31, active < 20
        const int q  = tid & 7;
        if (dd < DD) {
            float4 s = make_float4(0.f, 0.f, 0.f, 0.f);
            #pragma unroll
            for (int da = 0; da < 2; ++da)
                #pragma unroll
                for (int db = 0; db < 2; ++db)
                    #pragma unroll
                    for (int dc = 0; dc < 2; ++dc) {
                        const float4 v = *(const float4*)(
                            H + (size_t)((((a + da) * DD + (b + db)) * DD + (c + dc)) * DD + dd) * MM + q * 4);
                        s.x += v.x; s.y += v.y; s.z += v.z; s.w += v.w;
                    }
            ((float4*)(sS + dd * MM))[q] = s;
        }
    }
    __syncthreads();

    // phase 1.5: window rows  sW[d][j] = (sS[d][j] + sS[d+1][j]) / 16
    for (int idx = tid; idx < OO * MM; idx += 256) {
        const int d = idx >> 5, j = idx & 31;
        sW[d * SWS + j] = (sS[d * MM + j] + sS[d * MM + MM + j]) * 0.0625f;
    }
    __syncthreads();

    // phase 2: x[d][i:i+2] = sum_j win[d][j] * Mt[j][i:i+2]
    for (int d = d0; d < d1; ++d) {
        float2 acc = make_float2(0.f, 0.f);
        #pragma unroll
        for (int j = 0; j < MM; ++j) {
            const float wj = sW[d * SWS + j];                    // broadcast
            const float2 mt = *(const float2*)(sMt + j * MM + i);
            acc.x += wj * mt.x;
            acc.y += wj * mt.y;
        }
        *(float2*)(sX + d * SWS + i) = acc;
    }
    __syncthreads();

    // phase 3: out[d][i:i+2] = sum_j x[d][j] * qp[j] * Ct[d][j][i:i+2]
    for (int d = d0; d < d1; ++d) {
        float xr[MM];
        #pragma unroll
        for (int jj = 0; jj < MM / 4; ++jj) {
            const float4 v = ((const float4*)(sX + d * SWS))[jj];
            xr[jj * 4 + 0] = v.x; xr[jj * 4 + 1] = v.y;
            xr[jj * 4 + 2] = v.z; xr[jj * 4 + 3] = v.w;
        }
        const float* __restrict__ ctd = Ct + d * (MM * MM) + i;
        float2 acc = make_float2(0.f, 0.f);
        #pragma unroll
        for (int j = 0; j < MM; ++j) {
            const float2 ct = *(const float2*)(ctd + j * MM);
            const float t = xr[j];
            acc.x += t * qp[j].x * ct.x;
            acc.y += t * qp[j].y * ct.y;
        }
        *(float2*)(out + (size_t)(blk * OO + d) * MM + i) = acc;
    }
}

extern "C" void kernel_launch(void* const* d_in, const int* in_sizes, int n_in,
                              void* d_out, int out_size, void* d_ws, size_t ws_size,
                              hipStream_t stream) {
    const float* H  = (const float*)d_in[0];   // hypervol [20,20,20,20,32]
    const float* Mw = (const float*)d_in[1];   // M_w [32,32]
    const float* P  = (const float*)d_in[2];   // P   [32,32]
    float* out = (float*)d_out;
    float* ws  = (float*)d_ws;

    const int tblocks = (WS_FLOATS + 255) / 256;  // 84
    build_tables_kernel<<<tblocks, 256, 0, stream>>>(Mw, P, ws);
    spatial_kernel<<<NBLK, 256, 0, stream>>>(H, ws, out);
}

// Round 3
// 122.974 us; speedup vs baseline: 3.0517x; 3.0517x over previous
//
#include <hip/hip_runtime.h>

// Problem constants
#define DD 20          // hypervol spatial extent per axis
#define MM 32          // channel count m
#define OO 19          // output extent per axis (DD - RANK + 1, RANK=2)
#define NBLK (OO*OO*OO)

// workspace layout (floats):
//   Ct[19][32][32]  transposed cosine table: Ct[k][j][i] = cos(2*pi*k/(i*32+j+2))
//   Pt[32][32]      P transposed:  Pt[j][i] = P[i][j]
//   Mt[32][32]      M_w transposed: Mt[j][i] = M_w[i][j]
#define CT_FLOATS (OO*MM*MM)         // 19456
#define PT_OFF CT_FLOATS             // 19456
#define MT_OFF (PT_OFF + MM*MM)      // 20480
#define WS_FLOATS (MT_OFF + MM*MM)   // 21504

#define SRS 36   // padded LDS row stride (floats): 144 B = 16B-aligned, banks shift by 4/row

__global__ __launch_bounds__(256) void build_tables_kernel(
        const float* __restrict__ Mw, const float* __restrict__ P,
        float* __restrict__ ws) {
    int idx = blockIdx.x * 256 + threadIdx.x;
    if (idx < CT_FLOATS) {
        int k = idx >> 10;        // axis position 0..18
        int r = idx & 1023;
        int j = r >> 5;           // transposed: slow index is j
        int i = r & 31;
        float period = (float)(i * MM + j + 2);
        ws[idx] = cosf(6.28318530717958647692f * (float)k / period);
    } else if (idx < MT_OFF) {
        int r = idx - PT_OFF;
        ws[idx] = P[(r & 31) * MM + (r >> 5)];     // Pt[j][i] = P[i][j]
    } else if (idx < WS_FLOATS) {
        int r = idx - MT_OFF;
        ws[idx] = Mw[(r & 31) * MM + (r >> 5)];    // Mt[j][i] = Mw[i][j]
    }
}

// One block per (a,b,c). 256 threads: i2 = tid&15 -> channel pair i = 2*i2;
// g = tid>>4 -> 16 d-groups; group g owns d = g and (if g<3) d = g+16.
// qp table lives in LDS (NOT registers -- Round-2's 216-VGPR occupancy collapse).
__global__ __launch_bounds__(256) void spatial_kernel(
        const float* __restrict__ H, const float* __restrict__ ws,
        float* __restrict__ out) {
    __shared__ float sS[DD * SRS];     // (a,b,c)-presums, padded rows   (2880 B)
    __shared__ float sX[OO * SRS];     // x rows, padded                 (2736 B)
    __shared__ float sMt[MM * MM];     // Mt staged                      (4096 B)
    __shared__ float sQPt[MM * MM];    // Pt .* Ct[a] .* Ct[b] .* Ct[c]  (4096 B)

    const int tid = threadIdx.x;
    const int i2  = tid & 15;
    const int i   = i2 * 2;
    const int g   = tid >> 4;

    // XCD-contiguous swizzle: each XCD's round-robin share becomes a contiguous
    // (a,b,c) slab (~3.4 MB of H < 4 MB per-XCD L2). 6859 = 3*858 + 5*857.
    const int raw = blockIdx.x;
    const int xcd = raw & 7;
    const int k   = raw >> 3;
    const int blk = (xcd < 3) ? (xcd * 858 + k) : (2574 + (xcd - 3) * 857 + k);
    const int c = blk % OO;
    const int b = (blk / OO) % OO;
    const int a = blk / (OO * OO);

    const float* __restrict__ Ct = ws;
    const float* __restrict__ Pt = ws + PT_OFF;
    const float* __restrict__ Mt = ws + MT_OFF;

    // stage Mt (coalesced, 1 float4/thread)
    ((float4*)sMt)[tid] = ((const float4*)Mt)[tid];

    // build sQPt = Pt .* Ct[a] .* Ct[b] .* Ct[c]  (coalesced float4, into LDS)
    {
        float4 p  = ((const float4*)Pt)[tid];
        float4 xa = ((const float4*)(Ct + a * (MM * MM)))[tid];
        float4 xb = ((const float4*)(Ct + b * (MM * MM)))[tid];
        float4 xc = ((const float4*)(Ct + c * (MM * MM)))[tid];
        float4 q;
        q.x = p.x * xa.x * xb.x * xc.x;
        q.y = p.y * xa.y * xb.y * xc.y;
        q.z = p.z * xa.z * xb.z * xc.z;
        q.w = p.w * xa.w * xb.w * xc.w;
        ((float4*)sQPt)[tid] = q;
    }

    // phase 1: 8-shift pre-sum over (a,b,c); thread = (dd, quad), float4 loads
    {
        const int dd = tid >> 3;   // 0..31, active < 20
        const int q  = tid & 7;
        if (dd < DD) {
            float4 s = make_float4(0.f, 0.f, 0.f, 0.f);
            #pragma unroll
            for (int da = 0; da < 2; ++da)
                #pragma unroll
                for (int db = 0; db < 2; ++db)
                    #pragma unroll
                    for (int dc = 0; dc < 2; ++dc) {
                        const float4 v = *(const float4*)(
                            H + (size_t)((((a + da) * DD + (b + db)) * DD + (c + dc)) * DD + dd) * MM + q * 4);
                        s.x += v.x; s.y += v.y; s.z += v.z; s.w += v.w;
                    }
            *(float4*)(sS + dd * SRS + q * 4) = s;
        }
    }
    __syncthreads();

    // phase 2: x[d][i:i+2] = sum_j ((S[d][j]+S[d+1][j])/16) * Mt[j][i:i+2]
    for (int d = g; d < OO; d += 16) {
        const float* __restrict__ s0 = sS + d * SRS;
        float2 acc = make_float2(0.f, 0.f);
        #pragma unroll
        for (int j = 0; j < MM; ++j) {
            const float wj = (s0[j] + s0[SRS + j]) * 0.0625f;     // broadcast reads
            const float2 mt = *(const float2*)(sMt + j * MM + i); // ds_read_b64
            acc.x += wj * mt.x;
            acc.y += wj * mt.y;
        }
        *(float2*)(sX + d * SRS + i) = acc;
    }
    __syncthreads();

    // phase 3: out[d][i:i+2] = sum_j x[d][j] * qp[j][i:i+2] * Ct[d][j][i:i+2]
    for (int d = g; d < OO; d += 16) {
        float xr[MM];                               // 32 VGPRs, hoisted x row
        #pragma unroll
        for (int jj = 0; jj < MM / 4; ++jj) {
            const float4 v = *(const float4*)(sX + d * SRS + jj * 4);
            xr[jj * 4 + 0] = v.x; xr[jj * 4 + 1] = v.y;
            xr[jj * 4 + 2] = v.z; xr[jj * 4 + 3] = v.w;
        }
        const float* __restrict__ ctd = Ct + d * (MM * MM) + i;
        float2 acc = make_float2(0.f, 0.f);
        #pragma unroll
        for (int j = 0; j < MM; ++j) {
            const float2 q  = *(const float2*)(sQPt + j * MM + i);  // ds_read_b64
            const float2 ct = *(const float2*)(ctd + j * MM);       // global dwordx2 (L2)
            const float t = xr[j];
            acc.x += t * q.x * ct.x;
            acc.y += t * q.y * ct.y;
        }
        *(float2*)(out + (size_t)(blk * OO + d) * MM + i) = acc;
    }
}

extern "C" void kernel_launch(void* const* d_in, const int* in_sizes, int n_in,
                              void* d_out, int out_size, void* d_ws, size_t ws_size,
                              hipStream_t stream) {
    const float* H  = (const float*)d_in[0];   // hypervol [20,20,20,20,32]
    const float* Mw = (const float*)d_in[1];   // M_w [32,32]
    const float* P  = (const float*)d_in[2];   // P   [32,32]
    float* out = (float*)d_out;
    float* ws  = (float*)d_ws;

    const int tblocks = (WS_FLOATS + 255) / 256;  // 84
    build_tables_kernel<<<tblocks, 256, 0, stream>>>(Mw, P, ws);
    spatial_kernel<<<NBLK, 256, 0, stream>>>(H, ws, out);
}

// Round 4
// 94.775 us; speedup vs baseline: 3.9596x; 1.2975x over previous
//
#include <hip/hip_runtime.h>

// Problem constants
#define DD 20          // hypervol spatial extent per axis
#define MM 32          // channel count m
#define OO 19          // output extent per axis (DD - RANK + 1, RANK=2)
#define NWIN (OO*OO*OO)                  // 6859 windows
#define WPB 4                            // windows per block (one per wave)
#define NBLK ((NWIN + WPB - 1) / WPB)    // 1715 blocks

// workspace layout (floats):
//   Ct[19][32][32]  transposed cosine table: Ct[k][j][i] = cos(2*pi*k/(i*32+j+2))
//   Pt[32][32]      Pt[j][i] = P[i][j]
//   Mt[32][32]      Mt[j][i] = M_w[i][j]
#define CT_FLOATS (OO*MM*MM)         // 19456
#define PT_OFF CT_FLOATS
#define MT_OFF (PT_OFF + MM*MM)
#define WS_FLOATS (MT_OFF + MM*MM)   // 21504

__global__ __launch_bounds__(256) void build_tables_kernel(
        const float* __restrict__ Mw, const float* __restrict__ P,
        float* __restrict__ ws) {
    int idx = blockIdx.x * 256 + threadIdx.x;
    if (idx < CT_FLOATS) {
        int k = idx >> 10;
        int r = idx & 1023;
        int j = r >> 5;
        int i = r & 31;
        float period = (float)(i * MM + j + 2);
        ws[idx] = cosf(6.28318530717958647692f * (float)k / period);
    } else if (idx < MT_OFF) {
        int r = idx - PT_OFF;
        ws[idx] = P[(r & 31) * MM + (r >> 5)];
    } else if (idx < WS_FLOATS) {
        int r = idx - MT_OFF;
        ws[idx] = Mw[(r & 31) * MM + (r >> 5)];
    }
}

// Wave-internal sync: drain memory counters + compiler scheduling fence.
// No runtime barrier instruction -> waves never convoy.
__device__ __forceinline__ void wave_sync() {
    __builtin_amdgcn_s_waitcnt(0);        // vmcnt(0) lgkmcnt(0) expcnt(0)
    __builtin_amdgcn_wave_barrier();
}

// One WAVE per (a,b,c) window; 4 independent windows per 256-thread block.
// Lane = (i = lane&31 output channel, h = lane>>5 j-half).
// Phase 3 uses the Chebyshev recurrence s_d = 2cosw*s_{d-1} - s_{d-2} with
// s_0 = qp, s_{-1} = qp*cosw  ->  zero global Ct loads in the hot loop.
__global__ __launch_bounds__(256, 4) void spatial_kernel(
        const float* __restrict__ H, const float* __restrict__ ws,
        float* __restrict__ out) {
    __shared__ __align__(16) float sS[WPB][DD * MM];   // 8-shift pre-sums (per wave)
    __shared__ __align__(16) float sW[WPB][OO * MM];   // window rows /16
    __shared__ __align__(16) float sX[WPB][OO * MM];   // x rows

    const int tid  = threadIdx.x;
    const int w    = tid >> 6;          // wave in block
    const int lane = tid & 63;
    const int i    = lane & 31;
    const int h    = lane >> 5;
    const int jb   = h * 16;            // this lane's j-half base

    // XCD-contiguous block swizzle (1715 = 3*215 + 5*214, bijective)
    const int raw = blockIdx.x;
    const int xcd = raw & 7;
    const int k   = raw >> 3;
    const int sb  = (xcd < 3) ? (xcd * 215 + k) : (645 + (xcd - 3) * 214 + k);
    const int win = sb * WPB + w;
    if (win >= NWIN) return;            // wave-uniform; no block barriers exist
    const int c = win % OO;
    const int b = (win / OO) % OO;
    const int a = win / (OO * OO);

    const float* __restrict__ Ct = ws;
    const float* __restrict__ Pt = ws + PT_OFF;
    const float* __restrict__ Mt = ws + MT_OFF;

    float* __restrict__ S = sS[w];
    float* __restrict__ W = sW[w];
    float* __restrict__ X = sX[w];

    // ---- phase 1: 8-shift (a,b,c) pre-sum, S[d'][j], 640 floats ----
    {
        float2 acc[5];
        #pragma unroll
        for (int kk = 0; kk < 5; ++kk) acc[kk] = make_float2(0.f, 0.f);
        #pragma unroll
        for (int da = 0; da < 2; ++da)
            #pragma unroll
            for (int db = 0; db < 2; ++db)
                #pragma unroll
                for (int dc = 0; dc < 2; ++dc) {
                    const float2* __restrict__ p = (const float2*)(
                        H + (size_t)((((a + da) * DD + (b + db)) * DD + (c + dc)) * DD) * MM);
                    #pragma unroll
                    for (int kk = 0; kk < 5; ++kk) {
                        const float2 v = p[kk * 64 + lane];
                        acc[kk].x += v.x; acc[kk].y += v.y;
                    }
                }
        #pragma unroll
        for (int kk = 0; kk < 5; ++kk)
            ((float2*)S)[kk * 64 + lane] = acc[kk];
    }
    wave_sync();

    // ---- phase 1.5: W[d][j] = (S[d][j] + S[d+1][j]) / 16, 608 floats ----
    #pragma unroll
    for (int t = 0; t < 10; ++t) {
        const int idx = t * 64 + lane;
        if (idx < OO * MM)
            W[idx] = (S[idx] + S[idx + MM]) * 0.0625f;
    }
    wave_sync();

    // ---- phase 2: x[d][i] = sum_j W[d][j] * Mt[j][i]  (j-half + shfl) ----
    {
        float mt[16];
        #pragma unroll
        for (int jj = 0; jj < 16; ++jj)
            mt[jj] = Mt[(jb + jj) * MM + i];

        #pragma unroll
        for (int d = 0; d < OO; ++d) {
            const float4* __restrict__ wr = (const float4*)(W + d * MM + jb);
            float t = 0.f;
            #pragma unroll
            for (int q = 0; q < 4; ++q) {
                const float4 v = wr[q];
                t += v.x * mt[q*4+0] + v.y * mt[q*4+1]
                   + v.z * mt[q*4+2] + v.w * mt[q*4+3];
            }
            t += __shfl_xor(t, 32, 64);
            if (h == 0) X[d * MM + i] = t;
        }
    }
    wave_sync();

    // ---- phase 3: out[d][i] = sum_j x[d][j]*qp[j][i]*cos(w_ij*d) ----
    // Chebyshev state: s1 = qp*cos(w*d), advanced by s' = t2c*s1 - s0.
    float s0[16], s1[16], t2c[16];
    {
        const float* __restrict__ cta = Ct + a * (MM * MM);
        const float* __restrict__ ctb = Ct + b * (MM * MM);
        const float* __restrict__ ctc = Ct + c * (MM * MM);
        const float* __restrict__ ct1 = Ct + 1 * (MM * MM);
        #pragma unroll
        for (int jj = 0; jj < 16; ++jj) {
            const int o = (jb + jj) * MM + i;
            const float qp  = Pt[o] * cta[o] * ctb[o] * ctc[o];
            const float cw  = ct1[o];
            t2c[jj] = cw + cw;
            s1[jj]  = qp;          // d = 0
            s0[jj]  = qp * cw;     // d = -1 (cos is even)
        }
    }
    const size_t obase = (size_t)win * (OO * MM);
    #pragma unroll
    for (int d = 0; d < OO; ++d) {
        const float4* __restrict__ xr = (const float4*)(X + d * MM + jb);
        float t = 0.f;
        #pragma unroll
        for (int q = 0; q < 4; ++q) {
            const float4 v = xr[q];
            t += v.x * s1[q*4+0] + v.y * s1[q*4+1]
               + v.z * s1[q*4+2] + v.w * s1[q*4+3];
        }
        #pragma unroll
        for (int jj = 0; jj < 16; ++jj) {     // advance recurrence
            const float nx = __builtin_fmaf(t2c[jj], s1[jj], -s0[jj]);
            s0[jj] = s1[jj];
            s1[jj] = nx;
        }
        t += __shfl_xor(t, 32, 64);
        if (h == 0) out[obase + d * MM + i] = t;
    }
}

extern "C" void kernel_launch(void* const* d_in, const int* in_sizes, int n_in,
                              void* d_out, int out_size, void* d_ws, size_t ws_size,
                              hipStream_t stream) {
    const float* H  = (const float*)d_in[0];   // hypervol [20,20,20,20,32]
    const float* Mw = (const float*)d_in[1];   // M_w [32,32]
    const float* P  = (const float*)d_in[2];   // P   [32,32]
    float* out = (float*)d_out;
    float* ws  = (float*)d_ws;

    const int tblocks = (WS_FLOATS + 255) / 256;  // 84
    build_tables_kernel<<<tblocks, 256, 0, stream>>>(Mw, P, ws);
    spatial_kernel<<<NBLK, 256, 0, stream>>>(H, ws, out);
}